// Round 1
// baseline (314.306 us; speedup 1.0000x reference)
//
#include <hip/hip_runtime.h>
#include <math.h>

#define BB 2
#define CC 64
#define NN 4096
#define RR 8
#define QBLK 64
#define KBLK 64
#define KSPLIT 2
#define SCALE 0.35355339059327373f  // 1/sqrt(8)

// ---------------------------------------------------------------------------
// Kernel 1: 1x1x1 conv projections.  q[b][n][8], k[b][8][n], v[b][64][n]
// One wave per 64 positions; x column held in registers; W via uniform s_loads.
// ---------------------------------------------------------------------------
__global__ __launch_bounds__(64) void proj_kernel(
    const float* __restrict__ x, const float* __restrict__ Wq,
    const float* __restrict__ Wk, const float* __restrict__ Wv,
    float* __restrict__ qbuf, float* __restrict__ kbuf, float* __restrict__ vbuf)
{
    const int p = blockIdx.x * 64 + threadIdx.x;   // 0 .. BB*NN-1
    const int b = p >> 12;
    const int n = p & (NN - 1);
    const float* xp = x + (size_t)b * CC * NN + n;

    float xc[CC];
#pragma unroll
    for (int c = 0; c < CC; ++c) xc[c] = xp[(size_t)c * NN];

    float aq[RR], ak[RR];
#pragma unroll
    for (int r = 0; r < RR; ++r) { aq[r] = 0.f; ak[r] = 0.f; }
#pragma unroll
    for (int c = 0; c < CC; ++c) {
        const float xv = xc[c];
#pragma unroll
        for (int r = 0; r < RR; ++r) {
            aq[r] = fmaf(Wq[r * CC + c], xv, aq[r]);
            ak[r] = fmaf(Wk[r * CC + c], xv, ak[r]);
        }
    }
#pragma unroll
    for (int r = 0; r < RR; ++r) {
        qbuf[((size_t)b * NN + n) * RR + r] = aq[r];
        kbuf[((size_t)b * RR + r) * NN + n] = ak[r];
    }

#pragma unroll
    for (int g = 0; g < 4; ++g) {   // v in 4 groups of 16 to cap live registers
        float av[16];
#pragma unroll
        for (int j = 0; j < 16; ++j) av[j] = 0.f;
#pragma unroll
        for (int c = 0; c < CC; ++c) {
            const float xv = xc[c];
#pragma unroll
            for (int j = 0; j < 16; ++j)
                av[j] = fmaf(Wv[(g * 16 + j) * CC + c], xv, av[j]);
        }
#pragma unroll
        for (int j = 0; j < 16; ++j)
            vbuf[((size_t)b * CC + g * 16 + j) * NN + n] = av[j];
    }
}

// ---------------------------------------------------------------------------
// Kernel 2: flash attention partials.
// Block = 256 thr handles QBLK=64 queries over NN/KSPLIT keys.
// Thread (qg = tid>>4, cg = tid&15) owns 4 queries x 4 channels.
// Softmax state per query reduced over the 16 cg lanes via shfl_xor.
// ---------------------------------------------------------------------------
__global__ __launch_bounds__(256) void attn_kernel(
    const float* __restrict__ qbuf, const float* __restrict__ kbuf,
    const float* __restrict__ vbuf, float* __restrict__ part_o,
    float* __restrict__ part_m, float* __restrict__ part_l)
{
    const int nqb = NN / QBLK;                 // 64
    const int blk = blockIdx.x;
    const int qb = blk % nqb;
    const int b  = (blk / nqb) % BB;
    const int ks = blk / (nqb * BB);
    const int q0 = qb * QBLK;
    const int k0base = ks * (NN / KSPLIT);
    const int tid = (int)threadIdx.x;
    const int qg = tid >> 4;                   // 0..15 -> queries q0+qg*4..+4
    const int cg = tid & 15;                   // 0..15 -> channels cg*4..+4

    __shared__ float k_lds[RR][KBLK];          // 2 KiB
    __shared__ float v_lds[CC][KBLK + 1];      // 16.25 KiB (+1 pad: stride 65)
    __shared__ float p_lds[KBLK][QBLK + 4];    // 17 KiB  (+4 pad: b128-aligned)

    // q for my 4 queries, pre-scaled
    float qreg[4][RR];
    {
        const float4* qp = (const float4*)&qbuf[((size_t)b * NN + q0 + qg * 4) * RR];
#pragma unroll
        for (int iq = 0; iq < 4; ++iq) {
            float4 a = qp[iq * 2], bq = qp[iq * 2 + 1];
            qreg[iq][0] = a.x * SCALE;  qreg[iq][1] = a.y * SCALE;
            qreg[iq][2] = a.z * SCALE;  qreg[iq][3] = a.w * SCALE;
            qreg[iq][4] = bq.x * SCALE; qreg[iq][5] = bq.y * SCALE;
            qreg[iq][6] = bq.z * SCALE; qreg[iq][7] = bq.w * SCALE;
        }
    }

    float m[4], l[4], acc[4][4];
#pragma unroll
    for (int iq = 0; iq < 4; ++iq) {
        m[iq] = -1e30f; l[iq] = 0.f;
#pragma unroll
        for (int ic = 0; ic < 4; ++ic) acc[iq][ic] = 0.f;
    }

    const int nch = (NN / KSPLIT) / KBLK;      // 32
    for (int ch = 0; ch < nch; ++ch) {
        const int k0 = k0base + ch * KBLK;
        __syncthreads();                        // prev chunk's LDS reads done
        for (int i = tid; i < RR * KBLK; i += 256) {
            int r = i >> 6, kk = i & 63;
            k_lds[r][kk] = kbuf[((size_t)b * RR + r) * NN + k0 + kk];
        }
        {
            const int kk = tid & 63;
            const int c0 = (tid >> 6) * 16;
#pragma unroll
            for (int j = 0; j < 16; ++j)
                v_lds[c0 + j][kk] = vbuf[((size_t)b * CC + c0 + j) * NN + k0 + kk];
        }
        __syncthreads();

        // scores: my 4 queries x keys kk = cg*4..+4
        float s[4][4];
#pragma unroll
        for (int iq = 0; iq < 4; ++iq)
#pragma unroll
            for (int ik = 0; ik < 4; ++ik) s[iq][ik] = 0.f;
#pragma unroll
        for (int r = 0; r < RR; ++r) {
            const float4 k4 = *(const float4*)&k_lds[r][cg * 4];
#pragma unroll
            for (int iq = 0; iq < 4; ++iq) {
                s[iq][0] = fmaf(qreg[iq][r], k4.x, s[iq][0]);
                s[iq][1] = fmaf(qreg[iq][r], k4.y, s[iq][1]);
                s[iq][2] = fmaf(qreg[iq][r], k4.z, s[iq][2]);
                s[iq][3] = fmaf(qreg[iq][r], k4.w, s[iq][3]);
            }
        }

        // online softmax update (all 16 cg lanes of a qg compute identically)
#pragma unroll
        for (int iq = 0; iq < 4; ++iq) {
            float cmax = fmaxf(fmaxf(s[iq][0], s[iq][1]), fmaxf(s[iq][2], s[iq][3]));
#pragma unroll
            for (int off = 1; off < 16; off <<= 1)
                cmax = fmaxf(cmax, __shfl_xor(cmax, off));
            const float mnew  = fmaxf(m[iq], cmax);
            const float alpha = __expf(m[iq] - mnew);
            float lsum = 0.f;
#pragma unroll
            for (int ik = 0; ik < 4; ++ik) {
                const float pv = __expf(s[iq][ik] - mnew);
                p_lds[cg * 4 + ik][qg * 4 + iq] = pv;
                lsum += pv;
            }
#pragma unroll
            for (int off = 1; off < 16; off <<= 1)
                lsum += __shfl_xor(lsum, off);
            l[iq] = l[iq] * alpha + lsum;
            m[iq] = mnew;
#pragma unroll
            for (int ic = 0; ic < 4; ++ic) acc[iq][ic] *= alpha;
        }
        __syncthreads();   // p_lds visible (safety; writers are same-wave anyway)

        // PV accumulate
#pragma unroll 4
        for (int kk = 0; kk < KBLK; ++kk) {
            const float4 p4 = *(const float4*)&p_lds[kk][qg * 4];
            float vv[4];
#pragma unroll
            for (int ic = 0; ic < 4; ++ic) vv[ic] = v_lds[cg * 4 + ic][kk];
#pragma unroll
            for (int ic = 0; ic < 4; ++ic) {
                acc[0][ic] = fmaf(p4.x, vv[ic], acc[0][ic]);
                acc[1][ic] = fmaf(p4.y, vv[ic], acc[1][ic]);
                acc[2][ic] = fmaf(p4.z, vv[ic], acc[2][ic]);
                acc[3][ic] = fmaf(p4.w, vv[ic], acc[3][ic]);
            }
        }
    }

    // partials (un-normalized); layout part_o[ks][b][c][n]
#pragma unroll
    for (int iq = 0; iq < 4; ++iq) {
        const int q = q0 + qg * 4 + iq;
#pragma unroll
        for (int ic = 0; ic < 4; ++ic) {
            const int c = cg * 4 + ic;
            part_o[(((size_t)ks * BB + b) * CC + c) * NN + q] = acc[iq][ic];
        }
        if (cg == 0) {
            part_m[((size_t)ks * BB + b) * NN + q] = m[iq];
            part_l[((size_t)ks * BB + b) * NN + q] = l[iq];
        }
    }
}

// ---------------------------------------------------------------------------
// Kernel 3: merge the KSPLIT partials + residual epilogue.
// ---------------------------------------------------------------------------
__global__ __launch_bounds__(256) void merge_kernel(
    const float* __restrict__ x, const float* __restrict__ gamma,
    const float* __restrict__ part_o, const float* __restrict__ part_m,
    const float* __restrict__ part_l, float* __restrict__ out)
{
    const int idx = blockIdx.x * 256 + (int)threadIdx.x;  // over BB*CC*NN
    const int n = idx & (NN - 1);
    const int b = idx >> 18;                              // idx / (CC*NN)
    const float g = gamma[0];
    const float m0 = part_m[(size_t)b * NN + n];
    const float m1 = part_m[((size_t)BB + b) * NN + n];
    const float l0 = part_l[(size_t)b * NN + n];
    const float l1 = part_l[((size_t)BB + b) * NN + n];
    const float M  = fmaxf(m0, m1);
    const float w0 = __expf(m0 - M), w1 = __expf(m1 - M);
    const float L  = fmaf(l0, w0, l1 * w1);
    const float o0 = part_o[idx];
    const float o1 = part_o[(size_t)BB * CC * NN + idx];
    const float o  = fmaf(o0, w0, o1 * w1) / L;
    out[idx] = fmaf(g, o, x[idx]);
}

// ---------------------------------------------------------------------------
extern "C" void kernel_launch(void* const* d_in, const int* in_sizes, int n_in,
                              void* d_out, int out_size, void* d_ws, size_t ws_size,
                              hipStream_t stream)
{
    const float* x     = (const float*)d_in[0];
    const float* Wq    = (const float*)d_in[1];
    const float* Wk    = (const float*)d_in[2];
    const float* Wv    = (const float*)d_in[3];
    const float* gamma = (const float*)d_in[4];
    float* out = (float*)d_out;

    float* ws     = (float*)d_ws;
    float* qbuf   = ws;                                   // BB*NN*RR
    float* kbuf   = qbuf   + (size_t)BB * NN * RR;        // BB*NN*RR
    float* vbuf   = kbuf   + (size_t)BB * NN * RR;        // BB*CC*NN
    float* part_o = vbuf   + (size_t)BB * CC * NN;        // KSPLIT*BB*CC*NN
    float* part_m = part_o + (size_t)KSPLIT * BB * CC * NN;
    float* part_l = part_m + (size_t)KSPLIT * BB * NN;
    // total ~6.95 MB of ws

    hipLaunchKernelGGL(proj_kernel, dim3(BB * NN / 64), dim3(64), 0, stream,
                       x, Wq, Wk, Wv, qbuf, kbuf, vbuf);
    hipLaunchKernelGGL(attn_kernel, dim3(KSPLIT * BB * (NN / QBLK)), dim3(256), 0, stream,
                       qbuf, kbuf, vbuf, part_o, part_m, part_l);
    hipLaunchKernelGGL(merge_kernel, dim3(BB * CC * NN / 256), dim3(256), 0, stream,
                       x, gamma, part_o, part_m, part_l, out);
}

// Round 2
// 120.046 us; speedup vs baseline: 2.6182x; 2.6182x over previous
//
#include <hip/hip_runtime.h>
#include <math.h>

#define BB 2
#define CC 64
#define NN 4096
#define RR 8
#define QBLK 64
#define KBLK 64
#define KSPLIT 2
#define SCALE 0.35355339059327373f  // 1/sqrt(8)

typedef _Float16 f16x8 __attribute__((ext_vector_type(8)));
typedef float f32x4 __attribute__((ext_vector_type(4)));

union H2U { _Float16 h; unsigned short u; };
static __device__ inline unsigned short f2h_bits(float f) {
    H2U c; c.h = (_Float16)f; return c.u;
}

// ---------------------------------------------------------------------------
// Kernel 1: projections, packed f16 for MFMA fragments.
//   qh[b][n][8]  f16, SCALE folded in       (QK^T B-operand: 16B/lane)
//   kh[b][n][8]  f16                        (QK^T A-operand: 16B/lane)
//   vph[b][g=n/8][c][j=n%8] f16             (PV  A-operand: 16B/lane)
// grid (BB*NN/64, 5): group 0 = q+k, groups 1..4 = v 16-channel quarters.
// ---------------------------------------------------------------------------
__global__ __launch_bounds__(64) void proj_kernel(
    const float* __restrict__ x, const float* __restrict__ Wq,
    const float* __restrict__ Wk, const float* __restrict__ Wv,
    _Float16* __restrict__ qh, _Float16* __restrict__ kh,
    _Float16* __restrict__ vph)
{
    const int p = blockIdx.x * 64 + (int)threadIdx.x;   // 0 .. BB*NN-1
    const int b = p >> 12;
    const int n = p & (NN - 1);
    const int grp = blockIdx.y;
    const float* xp = x + (size_t)b * CC * NN + n;

    float xc[CC];
#pragma unroll
    for (int c = 0; c < CC; ++c) xc[c] = xp[(size_t)c * NN];

    if (grp == 0) {
        float aq[RR], ak[RR];
#pragma unroll
        for (int r = 0; r < RR; ++r) { aq[r] = 0.f; ak[r] = 0.f; }
#pragma unroll
        for (int c = 0; c < CC; ++c) {
            const float xv = xc[c];
#pragma unroll
            for (int r = 0; r < RR; ++r) {
                aq[r] = fmaf(Wq[r * CC + c], xv, aq[r]);
                ak[r] = fmaf(Wk[r * CC + c], xv, ak[r]);
            }
        }
        ushort4 q_lo, q_hi, k_lo, k_hi;
        q_lo.x = f2h_bits(aq[0] * SCALE); q_lo.y = f2h_bits(aq[1] * SCALE);
        q_lo.z = f2h_bits(aq[2] * SCALE); q_lo.w = f2h_bits(aq[3] * SCALE);
        q_hi.x = f2h_bits(aq[4] * SCALE); q_hi.y = f2h_bits(aq[5] * SCALE);
        q_hi.z = f2h_bits(aq[6] * SCALE); q_hi.w = f2h_bits(aq[7] * SCALE);
        k_lo.x = f2h_bits(ak[0]); k_lo.y = f2h_bits(ak[1]);
        k_lo.z = f2h_bits(ak[2]); k_lo.w = f2h_bits(ak[3]);
        k_hi.x = f2h_bits(ak[4]); k_hi.y = f2h_bits(ak[5]);
        k_hi.z = f2h_bits(ak[6]); k_hi.w = f2h_bits(ak[7]);
        ushort4* qp = (ushort4*)(qh + ((size_t)b * NN + n) * 8);
        ushort4* kp = (ushort4*)(kh + ((size_t)b * NN + n) * 8);
        qp[0] = q_lo; qp[1] = q_hi;
        kp[0] = k_lo; kp[1] = k_hi;
    } else {
        const int c0 = (grp - 1) * 16;
        float av[16];
#pragma unroll
        for (int j = 0; j < 16; ++j) av[j] = 0.f;
#pragma unroll
        for (int c = 0; c < CC; ++c) {
            const float xv = xc[c];
#pragma unroll
            for (int j = 0; j < 16; ++j)
                av[j] = fmaf(Wv[(c0 + j) * CC + c], xv, av[j]);
        }
        _Float16* vb = vph + ((size_t)b * 512 + (n >> 3)) * 512 + (n & 7);
#pragma unroll
        for (int j = 0; j < 16; ++j)
            vb[(size_t)(c0 + j) * 8] = (_Float16)av[j];
    }
}

// ---------------------------------------------------------------------------
// Kernel 2: flash attention, MFMA f16.
// Block = 256 thr = 4 waves; QBLK=64 queries; KBLK=64 keys/chunk.
// Wave w: softmax owner of q-tile w; PV owner of c-quadrant w.
// Swapped QK^T: D[k][q] = mfma(K-frag, Q-frag) -> lane holds 16 k for 1 q.
// P staged in LDS [q][64k] f16, XOR-swizzled (byte ^= (q&7)<<4).
// ---------------------------------------------------------------------------
__global__ __launch_bounds__(256) void attn_kernel(
    const _Float16* __restrict__ qh, const _Float16* __restrict__ kh,
    const _Float16* __restrict__ vph, float* __restrict__ part_o,
    float* __restrict__ part_m, float* __restrict__ part_l)
{
    const int nqb = NN / QBLK;                 // 64
    const int blk = blockIdx.x;
    const int qb = blk % nqb;
    const int b  = (blk / nqb) % BB;
    const int ks = blk / (nqb * BB);
    const int q0 = qb * QBLK;
    const int k0base = ks * (NN / KSPLIT);
    const int tid = (int)threadIdx.x;
    const int wid = tid >> 6;                  // q-tile (softmax) / c-quad (PV)
    const int lane = tid & 63;
    const int lg = lane >> 4;                  // 0..3
    const int lc = lane & 15;                  // 0..15

    __shared__ __align__(16) unsigned char Pl[QBLK * 128];   // 8 KiB
    __shared__ float alpha_lds[QBLK];

    const f16x8 zf16 = {};
    const f32x4 zf32 = {};

    // Q fragment (B-operand): lanes 0-15 hold q-row's 8 r-values, rest zero.
    f16x8 qfrag;
    {
        f16x8 t = *(const f16x8*)(qh + ((size_t)b * NN + q0 + wid * 16 + lc) * 8);
        qfrag = (lg == 0) ? t : zf16;
    }

    float m = -1e30f, l = 0.f;                 // softmax state for q = qt*16+lc
    f32x4 acc[4];                              // PV acc, one D-tile per q-tile
#pragma unroll
    for (int qt = 0; qt < 4; ++qt) acc[qt] = zf32;

    const int nch = (NN / KSPLIT) / KBLK;      // 32
    for (int ch = 0; ch < nch; ++ch) {
        const int k0 = k0base + ch * KBLK;

        // ---- scores S[k][q] for my q-tile: 4 k-tiles ----
        f32x4 sacc[4];
#pragma unroll
        for (int kt = 0; kt < 4; ++kt) {
            f16x8 t = *(const f16x8*)(kh + ((size_t)b * NN + k0 + kt * 16 + lc) * 8);
            f16x8 kfrag = (lg == 0) ? t : zf16;
            sacc[kt] = __builtin_amdgcn_mfma_f32_16x16x32_f16(kfrag, qfrag, zf32, 0, 0, 0);
        }

        // ---- online softmax (lane holds k = kt*16 + lg*4 + v for one q) ----
        float s[16];
#pragma unroll
        for (int kt = 0; kt < 4; ++kt)
#pragma unroll
            for (int v = 0; v < 4; ++v) s[kt * 4 + v] = sacc[kt][v];
        float cmax = s[0];
#pragma unroll
        for (int i = 1; i < 16; ++i) cmax = fmaxf(cmax, s[i]);
        cmax = fmaxf(cmax, __shfl_xor(cmax, 16));
        cmax = fmaxf(cmax, __shfl_xor(cmax, 32));
        const float mnew  = fmaxf(m, cmax);
        const float alpha = __expf(m - mnew);
        float p[16], lsum = 0.f;
#pragma unroll
        for (int i = 0; i < 16; ++i) { p[i] = __expf(s[i] - mnew); lsum += p[i]; }
        lsum += __shfl_xor(lsum, 16);
        lsum += __shfl_xor(lsum, 32);
        l = l * alpha + lsum;
        m = mnew;

        __syncthreads();   // all waves done reading previous chunk's P
        {
            const int q = wid * 16 + lc;
            alpha_lds[q] = alpha;              // dup writes across lg, same value
#pragma unroll
            for (int kt = 0; kt < 4; ++kt) {
                ushort4 pk;
                pk.x = f2h_bits(p[kt * 4 + 0]);
                pk.y = f2h_bits(p[kt * 4 + 1]);
                pk.z = f2h_bits(p[kt * 4 + 2]);
                pk.w = f2h_bits(p[kt * 4 + 3]);
                int off = q * 128 + kt * 32 + lg * 8;
                off ^= (q & 7) << 4;
                *(ushort4*)(&Pl[off]) = pk;
            }
        }
        __syncthreads();   // P + alpha visible

        // ---- PV: acc[c-quad wid][q-tile qt] += V * P ----
        f16x8 vfrag[2];
#pragma unroll
        for (int kf = 0; kf < 2; ++kf) {
            const int g = (k0 >> 3) + kf * 4 + lg;
            vfrag[kf] = *(const f16x8*)(vph + ((size_t)b * 512 + g) * 512 + (wid * 16 + lc) * 8);
        }
#pragma unroll
        for (int qt = 0; qt < 4; ++qt) {
            const int qq = qt * 16 + lc;
            const float a = alpha_lds[qq];
            acc[qt] *= a;
#pragma unroll
            for (int kf = 0; kf < 2; ++kf) {
                int off = qq * 128 + kf * 64 + lg * 16;
                off ^= (qq & 7) << 4;
                f16x8 pfrag = *(const f16x8*)(&Pl[off]);
                acc[qt] = __builtin_amdgcn_mfma_f32_16x16x32_f16(vfrag[kf], pfrag, acc[qt], 0, 0, 0);
            }
        }
    }

    // ---- partials: part_o[ks][b][c][n] (un-normalized), m/l per query ----
    const size_t base_o = ((size_t)(ks * BB + b) * CC + wid * 16 + lg * 4) * NN + q0;
#pragma unroll
    for (int qt = 0; qt < 4; ++qt)
#pragma unroll
        for (int v = 0; v < 4; ++v)
            part_o[base_o + (size_t)v * NN + qt * 16 + lc] = acc[qt][v];
    if (lg == 0) {
        part_m[(size_t)(ks * BB + b) * NN + q0 + wid * 16 + lc] = m;
        part_l[(size_t)(ks * BB + b) * NN + q0 + wid * 16 + lc] = l;
    }
}

// ---------------------------------------------------------------------------
// Kernel 3: merge KSPLIT partials + residual epilogue.
// ---------------------------------------------------------------------------
__global__ __launch_bounds__(256) void merge_kernel(
    const float* __restrict__ x, const float* __restrict__ gamma,
    const float* __restrict__ part_o, const float* __restrict__ part_m,
    const float* __restrict__ part_l, float* __restrict__ out)
{
    const int idx = blockIdx.x * 256 + (int)threadIdx.x;  // over BB*CC*NN
    const int n = idx & (NN - 1);
    const int b = idx >> 18;
    const float g = gamma[0];
    const float m0 = part_m[(size_t)b * NN + n];
    const float m1 = part_m[((size_t)BB + b) * NN + n];
    const float l0 = part_l[(size_t)b * NN + n];
    const float l1 = part_l[((size_t)BB + b) * NN + n];
    const float M  = fmaxf(m0, m1);
    const float w0 = __expf(m0 - M), w1 = __expf(m1 - M);
    const float L  = fmaf(l0, w0, l1 * w1);
    const float o0 = part_o[idx];
    const float o1 = part_o[(size_t)BB * CC * NN + idx];
    const float o  = fmaf(o0, w0, o1 * w1) / L;
    out[idx] = fmaf(g, o, x[idx]);
}

// ---------------------------------------------------------------------------
extern "C" void kernel_launch(void* const* d_in, const int* in_sizes, int n_in,
                              void* d_out, int out_size, void* d_ws, size_t ws_size,
                              hipStream_t stream)
{
    const float* x     = (const float*)d_in[0];
    const float* Wq    = (const float*)d_in[1];
    const float* Wk    = (const float*)d_in[2];
    const float* Wv    = (const float*)d_in[3];
    const float* gamma = (const float*)d_in[4];
    float* out = (float*)d_out;

    // ws layout (bytes):
    //   qh   : BB*NN*8 f16           = 128 KiB
    //   kh   : BB*NN*8 f16           = 128 KiB
    //   vph  : BB*512*64*8 f16       = 1 MiB
    //   part_o: KSPLIT*BB*CC*NN f32  = 4 MiB
    //   part_m/part_l: KSPLIT*BB*NN f32 each
    char* ws = (char*)d_ws;
    _Float16* qh  = (_Float16*)ws;
    _Float16* kh  = qh  + (size_t)BB * NN * 8;
    _Float16* vph = kh  + (size_t)BB * NN * 8;
    float* part_o = (float*)(vph + (size_t)BB * 512 * 512);
    float* part_m = part_o + (size_t)KSPLIT * BB * CC * NN;
    float* part_l = part_m + (size_t)KSPLIT * BB * NN;

    hipLaunchKernelGGL(proj_kernel, dim3(BB * NN / 64, 5), dim3(64), 0, stream,
                       x, Wq, Wk, Wv, qh, kh, vph);
    hipLaunchKernelGGL(attn_kernel, dim3(KSPLIT * BB * (NN / QBLK)), dim3(256), 0, stream,
                       qh, kh, vph, part_o, part_m, part_l);
    hipLaunchKernelGGL(merge_kernel, dim3(BB * CC * NN / 256), dim3(256), 0, stream,
                       x, gamma, part_o, part_m, part_l, out);
}

// Round 5
// 106.204 us; speedup vs baseline: 2.9595x; 1.1303x over previous
//
#include <hip/hip_runtime.h>
#include <math.h>

#define BB 2
#define CC 64
#define NN 4096
#define RR 8
#define KSPLIT 4
#define SCALE 0.35355339059327373f  // 1/sqrt(8)

typedef _Float16 f16x8 __attribute__((ext_vector_type(8)));
typedef _Float16 f16x4 __attribute__((ext_vector_type(4)));
typedef float f32x4 __attribute__((ext_vector_type(4)));

// ---------------------------------------------------------------------------
// Kernel 1: projections. thread t -> grp = t>>13 (0..9), position p = t&8191.
//   grp 0: q[0..7] (SCALE folded) -> qh[b][n][8] f16 (one 16B store)
//   grp 1: k[0..7]                -> kh[b][n][8] f16
//   grp 2..9: v 8-channel slice   -> vph[b][n/8][c][n%8] f16
// ---------------------------------------------------------------------------
__global__ __launch_bounds__(256) void proj_kernel(
    const float* __restrict__ x, const float* __restrict__ Wq,
    const float* __restrict__ Wk, const float* __restrict__ Wv,
    _Float16* __restrict__ qh, _Float16* __restrict__ kh,
    _Float16* __restrict__ vph)
{
    const int t = (int)blockIdx.x * 256 + (int)threadIdx.x;   // 0..81919
    const int grp = t >> 13;                                  // 0..9
    const int p = t & 8191;
    const int b = p >> 12;
    const int n = p & (NN - 1);
    const float* xp = x + (size_t)b * CC * NN + n;

    float xc[CC];
#pragma unroll
    for (int c = 0; c < CC; ++c) xc[c] = xp[(size_t)c * NN];

    const float* W = (grp == 0) ? Wq : (grp == 1) ? Wk
                                     : (Wv + (size_t)(grp - 2) * 8 * CC);
    float a[8];
#pragma unroll
    for (int j = 0; j < 8; ++j) a[j] = 0.f;
#pragma unroll
    for (int c = 0; c < CC; ++c) {
        const float xv = xc[c];
#pragma unroll
        for (int j = 0; j < 8; ++j)
            a[j] = fmaf(W[j * CC + c], xv, a[j]);
    }
    if (grp == 0) {
        f16x8 o;
#pragma unroll
        for (int j = 0; j < 8; ++j) o[j] = (_Float16)(a[j] * SCALE);
        *(f16x8*)(qh + ((size_t)b * NN + n) * 8) = o;
    } else if (grp == 1) {
        f16x8 o;
#pragma unroll
        for (int j = 0; j < 8; ++j) o[j] = (_Float16)a[j];
        *(f16x8*)(kh + ((size_t)b * NN + n) * 8) = o;
    } else {
        const int c0 = (grp - 2) * 8;
        _Float16* vb = vph + ((size_t)(b * 512 + (n >> 3)) * CC + c0) * 8 + (n & 7);
#pragma unroll
        for (int j = 0; j < 8; ++j) vb[j * 8] = (_Float16)a[j];
    }
}

// ---------------------------------------------------------------------------
// Kernel 2: flash attention, barrier-free, LDS-free.
// Wave gw = blockIdx*4+wid owns (ks, b, 16 queries); waves fully independent.
// Swapped QK^T -> lane holds 8 scores of q=lane&15; softmax lane-local;
// P redistributed to the PV B-fragment layout with 8 shfl.
// ---------------------------------------------------------------------------
__global__ __launch_bounds__(256) void attn_kernel(
    const _Float16* __restrict__ qh, const _Float16* __restrict__ kh,
    const _Float16* __restrict__ vph, _Float16* __restrict__ part_o,
    float* __restrict__ part_m, float* __restrict__ part_l)
{
    const int tid = (int)threadIdx.x;
    const int wid = tid >> 6;
    const int lane = tid & 63;
    const int lg = lane >> 4;                      // 0..3
    const int lc = lane & 15;                      // 0..15
    const int gw = (int)blockIdx.x * 4 + wid;      // 0..2047
    const int qi = gw & 255;
    const int b  = (gw >> 8) & 1;
    const int ks = gw >> 9;                        // 0..3
    const int q0 = qi * 16;

    const f16x8 zf = {};
    const f32x4 z4 = {};

    f16x8 qfrag = zf;
    if (lg == 0)
        qfrag = *(const f16x8*)(qh + ((size_t)b * NN + q0 + lc) * 8);

    float m = -1e30f, l = 0.f;
    f32x4 acc0 = z4, acc1 = z4, acc2 = z4, acc3 = z4;

    const _Float16* khb = kh + (size_t)b * NN * 8;
    const _Float16* vpb = vph + (size_t)b * 512 * CC * 8;

    for (int ch = 0; ch < 32; ++ch) {
        const int k0 = ks * 1024 + ch * 32;

        // QK^T: D[k][q] for 2 k-tiles of 16
        f16x8 kf0 = zf, kf1 = zf;
        if (lg == 0) {
            kf0 = *(const f16x8*)(khb + (size_t)(k0 + lc) * 8);
            kf1 = *(const f16x8*)(khb + (size_t)(k0 + 16 + lc) * 8);
        }
        f32x4 s0 = __builtin_amdgcn_mfma_f32_16x16x32_f16(kf0, qfrag, z4, 0, 0, 0);
        f32x4 s1 = __builtin_amdgcn_mfma_f32_16x16x32_f16(kf1, qfrag, z4, 0, 0, 0);

        // chunk max for my q (= lc); k-rows live across lg -> xor 16, 32
        float cm = fmaxf(fmaxf(fmaxf(s0[0], s0[1]), fmaxf(s0[2], s0[3])),
                         fmaxf(fmaxf(s1[0], s1[1]), fmaxf(s1[2], s1[3])));
        cm = fmaxf(cm, __shfl_xor(cm, 16));
        cm = fmaxf(cm, __shfl_xor(cm, 32));

        if (!__all(cm <= m)) {                     // deferred-max (THR=0, p<=1)
            const float mnew = fmaxf(m, cm);
            const float alpha = __expf(m - mnew);
            m = mnew;
            l *= alpha;
            acc0 *= alpha; acc1 *= alpha; acc2 *= alpha; acc3 *= alpha;
        }

        float pr[8];
        float ls = 0.f;
#pragma unroll
        for (int v = 0; v < 4; ++v) { pr[v]     = __expf(s0[v] - m); ls += pr[v]; }
#pragma unroll
        for (int v = 0; v < 4; ++v) { pr[4 + v] = __expf(s1[v] - m); ls += pr[4 + v]; }
        ls += __shfl_xor(ls, 16);
        ls += __shfl_xor(ls, 32);
        l += ls;

        // pack P to f16, redistribute to PV B-fragment layout:
        // target lane (lg,lc) needs P[kk=lg*8+j][q=lc]; sources are tile
        // (lg>>1? no: lg*8's k-tile) lanes ((2lg)&3)*16+lc, ((2lg+1)&3)*16+lc.
        union { f16x4 h; unsigned u[2]; } P0, P1;
#pragma unroll
        for (int v = 0; v < 4; ++v) {
            P0.h[v] = (_Float16)pr[v];
            P1.h[v] = (_Float16)pr[4 + v];
        }
        const int sA = (((2 * lg) & 3) << 4) + lc;
        const int sB = (((2 * lg + 1) & 3) << 4) + lc;
        const unsigned t00 = __shfl(P0.u[0], sA), t01 = __shfl(P0.u[1], sA);
        const unsigned t10 = __shfl(P1.u[0], sA), t11 = __shfl(P1.u[1], sA);
        const unsigned u00 = __shfl(P0.u[0], sB), u01 = __shfl(P0.u[1], sB);
        const unsigned u10 = __shfl(P1.u[0], sB), u11 = __shfl(P1.u[1], sB);
        const bool hi = (lg & 2) != 0;
        union { unsigned u[4]; f16x8 v; } PF;
        PF.u[0] = hi ? t10 : t00;
        PF.u[1] = hi ? t11 : t01;
        PF.u[2] = hi ? u10 : u00;
        PF.u[3] = hi ? u11 : u01;

        // PV: acc[ct] += V[c][k] * P[k][q]
        const _Float16* vg = vpb + ((size_t)((k0 >> 3) + lg) * CC) * 8;
        f16x8 v0 = *(const f16x8*)(vg + (0 * 16 + lc) * 8);
        f16x8 v1 = *(const f16x8*)(vg + (1 * 16 + lc) * 8);
        f16x8 v2 = *(const f16x8*)(vg + (2 * 16 + lc) * 8);
        f16x8 v3 = *(const f16x8*)(vg + (3 * 16 + lc) * 8);
        acc0 = __builtin_amdgcn_mfma_f32_16x16x32_f16(v0, PF.v, acc0, 0, 0, 0);
        acc1 = __builtin_amdgcn_mfma_f32_16x16x32_f16(v1, PF.v, acc1, 0, 0, 0);
        acc2 = __builtin_amdgcn_mfma_f32_16x16x32_f16(v2, PF.v, acc2, 0, 0, 0);
        acc3 = __builtin_amdgcn_mfma_f32_16x16x32_f16(v3, PF.v, acc3, 0, 0, 0);
    }

    // partials: part_o[ks][b][c][n] f16 (un-normalized)
    _Float16* po = part_o + (size_t)(ks * BB + b) * CC * NN + q0 + lc;
#pragma unroll
    for (int v = 0; v < 4; ++v) {
        po[(size_t)(0 * 16 + lg * 4 + v) * NN] = (_Float16)acc0[v];
        po[(size_t)(1 * 16 + lg * 4 + v) * NN] = (_Float16)acc1[v];
        po[(size_t)(2 * 16 + lg * 4 + v) * NN] = (_Float16)acc2[v];
        po[(size_t)(3 * 16 + lg * 4 + v) * NN] = (_Float16)acc3[v];
    }
    if (lane < 16) {
        part_m[(size_t)(ks * BB + b) * NN + q0 + lc] = m;
        part_l[(size_t)(ks * BB + b) * NN + q0 + lc] = l;
    }
}

// ---------------------------------------------------------------------------
// Kernel 3: merge KSPLIT partials + residual epilogue.
// ---------------------------------------------------------------------------
__global__ __launch_bounds__(256) void merge_kernel(
    const float* __restrict__ x, const float* __restrict__ gamma,
    const _Float16* __restrict__ part_o, const float* __restrict__ part_m,
    const float* __restrict__ part_l, float* __restrict__ out)
{
    const int idx = (int)blockIdx.x * 256 + (int)threadIdx.x;  // over BB*CC*NN
    const int n = idx & (NN - 1);
    const int b = idx >> 18;
    const float g = gamma[0];
    float mv[KSPLIT], lv[KSPLIT];
#pragma unroll
    for (int ks = 0; ks < KSPLIT; ++ks) {
        mv[ks] = part_m[(size_t)(ks * BB + b) * NN + n];
        lv[ks] = part_l[(size_t)(ks * BB + b) * NN + n];
    }
    float M = fmaxf(fmaxf(mv[0], mv[1]), fmaxf(mv[2], mv[3]));
    float L = 0.f, o = 0.f;
#pragma unroll
    for (int ks = 0; ks < KSPLIT; ++ks) {
        const float w = __expf(mv[ks] - M);
        L = fmaf(lv[ks], w, L);
        o = fmaf((float)part_o[(size_t)ks * (BB * CC * NN) + idx], w, o);
    }
    out[idx] = fmaf(g, o / L, x[idx]);
}

// ---------------------------------------------------------------------------
extern "C" void kernel_launch(void* const* d_in, const int* in_sizes, int n_in,
                              void* d_out, int out_size, void* d_ws, size_t ws_size,
                              hipStream_t stream)
{
    const float* x     = (const float*)d_in[0];
    const float* Wq    = (const float*)d_in[1];
    const float* Wk    = (const float*)d_in[2];
    const float* Wv    = (const float*)d_in[3];
    const float* gamma = (const float*)d_in[4];
    float* out = (float*)d_out;

    // ws layout: qh 128K | kh 128K | vph 1M | part_o(f16) 4M | part_m/l 128K ea
    char* ws = (char*)d_ws;
    _Float16* qh     = (_Float16*)ws;
    _Float16* kh     = qh  + (size_t)BB * NN * 8;
    _Float16* vph    = kh  + (size_t)BB * NN * 8;
    _Float16* part_o = vph + (size_t)BB * 512 * CC * 8;
    float* part_m = (float*)(part_o + (size_t)KSPLIT * BB * CC * NN);
    float* part_l = part_m + (size_t)KSPLIT * BB * NN;

    hipLaunchKernelGGL(proj_kernel, dim3(320), dim3(256), 0, stream,
                       x, Wq, Wk, Wv, qh, kh, vph);
    hipLaunchKernelGGL(attn_kernel, dim3(512), dim3(256), 0, stream,
                       qh, kh, vph, part_o, part_m, part_l);
    hipLaunchKernelGGL(merge_kernel, dim3(BB * CC * NN / 256), dim3(256), 0, stream,
                       x, gamma, part_o, part_m, part_l, out);
}

// Round 6
// 90.532 us; speedup vs baseline: 3.4718x; 1.1731x over previous
//
#include <hip/hip_runtime.h>
#include <math.h>

#define BB 2
#define CC 64
#define NN 4096
#define SCALE 0.35355339059327373f  // 1/sqrt(8)

typedef _Float16 f16x8 __attribute__((ext_vector_type(8)));
typedef _Float16 f16x4 __attribute__((ext_vector_type(4)));
typedef float f32x4 __attribute__((ext_vector_type(4)));

// ---------------------------------------------------------------------------
// Kernel 1: projections. thread t -> grp = t>>13 (0..9), position p = t&8191.
//   grp 0: q[0..7] (SCALE folded) -> qh[b][n][8] f16 (one 16B store)
//   grp 1: k[0..7]                -> kh[b][n][8] f16
//   grp 2..9: v 8-channel slice   -> vph[b][n/8][c][n%8] f16
// ---------------------------------------------------------------------------
__global__ __launch_bounds__(256) void proj_kernel(
    const float* __restrict__ x, const float* __restrict__ Wq,
    const float* __restrict__ Wk, const float* __restrict__ Wv,
    _Float16* __restrict__ qh, _Float16* __restrict__ kh,
    _Float16* __restrict__ vph)
{
    const int t = (int)blockIdx.x * 256 + (int)threadIdx.x;   // 0..81919
    const int grp = t >> 13;                                  // 0..9
    const int p = t & 8191;
    const int b = p >> 12;
    const int n = p & (NN - 1);
    const float* xp = x + (size_t)b * CC * NN + n;

    float xc[CC];
#pragma unroll
    for (int c = 0; c < CC; ++c) xc[c] = xp[(size_t)c * NN];

    const float* W = (grp == 0) ? Wq : (grp == 1) ? Wk
                                     : (Wv + (size_t)(grp - 2) * 8 * CC);
    float a[8];
#pragma unroll
    for (int j = 0; j < 8; ++j) a[j] = 0.f;
#pragma unroll
    for (int c = 0; c < CC; ++c) {
        const float xv = xc[c];
#pragma unroll
        for (int j = 0; j < 8; ++j)
            a[j] = fmaf(W[j * CC + c], xv, a[j]);
    }
    if (grp == 0) {
        f16x8 o;
#pragma unroll
        for (int j = 0; j < 8; ++j) o[j] = (_Float16)(a[j] * SCALE);
        *(f16x8*)(qh + ((size_t)b * NN + n) * 8) = o;
    } else if (grp == 1) {
        f16x8 o;
#pragma unroll
        for (int j = 0; j < 8; ++j) o[j] = (_Float16)a[j];
        *(f16x8*)(kh + ((size_t)b * NN + n) * 8) = o;
    } else {
        const int c0 = (grp - 2) * 8;
        _Float16* vb = vph + ((size_t)(b * 512 + (n >> 3)) * CC + c0) * 8 + (n & 7);
#pragma unroll
        for (int j = 0; j < 8; ++j) vb[j * 8] = (_Float16)a[j];
    }
}

// ---------------------------------------------------------------------------
// Kernel 2: fused flash attention + split-K merge + residual epilogue.
// Block = 512 thr = 8 waves; block owns (b, 16 queries); wave w owns keys
// [512w, 512w+512).  Main loop: barrier-free, LDS-free (verified R5 path:
// swapped QK^T, lane-local softmax, 8-shfl P redistribution).  Epilogue:
// per-wave (m,l,acc) -> LDS (acc stride 17: conflict-free writes), one
// barrier, 8-way weighted merge, out = x + g * O/L.
// ---------------------------------------------------------------------------
__global__ __launch_bounds__(512) void attn_kernel(
    const _Float16* __restrict__ qh, const _Float16* __restrict__ kh,
    const _Float16* __restrict__ vph, const float* __restrict__ x,
    const float* __restrict__ gamma, float* __restrict__ out)
{
    const int tid = (int)threadIdx.x;
    const int wid = tid >> 6;                      // 0..7 = K-split slice
    const int lane = tid & 63;
    const int lg = lane >> 4;                      // 0..3
    const int lc = lane & 15;                      // 0..15
    const int qi = (int)blockIdx.x & 255;
    const int b  = (int)blockIdx.x >> 8;
    const int q0 = qi * 16;

    __shared__ float sm_acc[8 * 64 * 17];          // 34816 B, stride-17 pad
    __shared__ float sm_m[8][16];
    __shared__ float sm_l[8][16];

    const f16x8 zf = {};
    const f32x4 z4 = {};

    f16x8 qfrag = zf;
    if (lg == 0)
        qfrag = *(const f16x8*)(qh + ((size_t)b * NN + q0 + lc) * 8);

    float m = -1e30f, l = 0.f;
    f32x4 acc0 = z4, acc1 = z4, acc2 = z4, acc3 = z4;

    const _Float16* khb = kh + (size_t)b * NN * 8;
    const _Float16* vpb = vph + (size_t)b * 512 * CC * 8;
    const int kbase = wid * 512;

#pragma unroll 4
    for (int ch = 0; ch < 16; ++ch) {
        const int k0 = kbase + ch * 32;

        // QK^T: D[k][q] for 2 k-tiles of 16
        f16x8 kf0 = zf, kf1 = zf;
        if (lg == 0) {
            kf0 = *(const f16x8*)(khb + (size_t)(k0 + lc) * 8);
            kf1 = *(const f16x8*)(khb + (size_t)(k0 + 16 + lc) * 8);
        }
        // V fragments (independent of softmax -> compiler hoists early)
        const _Float16* vg = vpb + ((size_t)((k0 >> 3) + lg) * CC) * 8;
        f16x8 v0 = *(const f16x8*)(vg + (0 * 16 + lc) * 8);
        f16x8 v1 = *(const f16x8*)(vg + (1 * 16 + lc) * 8);
        f16x8 v2 = *(const f16x8*)(vg + (2 * 16 + lc) * 8);
        f16x8 v3 = *(const f16x8*)(vg + (3 * 16 + lc) * 8);

        f32x4 s0 = __builtin_amdgcn_mfma_f32_16x16x32_f16(kf0, qfrag, z4, 0, 0, 0);
        f32x4 s1 = __builtin_amdgcn_mfma_f32_16x16x32_f16(kf1, qfrag, z4, 0, 0, 0);

        // chunk max for my q (= lc); k-rows live across lg -> xor 16, 32
        float cm = fmaxf(fmaxf(fmaxf(s0[0], s0[1]), fmaxf(s0[2], s0[3])),
                         fmaxf(fmaxf(s1[0], s1[1]), fmaxf(s1[2], s1[3])));
        cm = fmaxf(cm, __shfl_xor(cm, 16));
        cm = fmaxf(cm, __shfl_xor(cm, 32));

        if (!__all(cm <= m)) {                     // deferred-max (THR=0, p<=1)
            const float mnew = fmaxf(m, cm);
            const float alpha = __expf(m - mnew);
            m = mnew;
            l *= alpha;
            acc0 *= alpha; acc1 *= alpha; acc2 *= alpha; acc3 *= alpha;
        }

        float pr[8];
        float ls = 0.f;
#pragma unroll
        for (int v = 0; v < 4; ++v) { pr[v]     = __expf(s0[v] - m); ls += pr[v]; }
#pragma unroll
        for (int v = 0; v < 4; ++v) { pr[4 + v] = __expf(s1[v] - m); ls += pr[4 + v]; }
        ls += __shfl_xor(ls, 16);
        ls += __shfl_xor(ls, 32);
        l += ls;

        // pack P to f16, redistribute to PV B-fragment layout (verified R5):
        // target lane (lg,lc) needs P[kk=lg*8+j][q=lc].
        union { f16x4 h; unsigned u[2]; } P0, P1;
#pragma unroll
        for (int v = 0; v < 4; ++v) {
            P0.h[v] = (_Float16)pr[v];
            P1.h[v] = (_Float16)pr[4 + v];
        }
        const int sA = (((2 * lg) & 3) << 4) + lc;
        const int sB = (((2 * lg + 1) & 3) << 4) + lc;
        const unsigned t00 = __shfl(P0.u[0], sA), t01 = __shfl(P0.u[1], sA);
        const unsigned t10 = __shfl(P1.u[0], sA), t11 = __shfl(P1.u[1], sA);
        const unsigned u00 = __shfl(P0.u[0], sB), u01 = __shfl(P0.u[1], sB);
        const unsigned u10 = __shfl(P1.u[0], sB), u11 = __shfl(P1.u[1], sB);
        const bool hi = (lg & 2) != 0;
        union { unsigned u[4]; f16x8 v; } PF;
        PF.u[0] = hi ? t10 : t00;
        PF.u[1] = hi ? t11 : t01;
        PF.u[2] = hi ? u10 : u00;
        PF.u[3] = hi ? u11 : u01;

        // PV: acc[ct] += V[c][k] * P[k][q]
        acc0 = __builtin_amdgcn_mfma_f32_16x16x32_f16(v0, PF.v, acc0, 0, 0, 0);
        acc1 = __builtin_amdgcn_mfma_f32_16x16x32_f16(v1, PF.v, acc1, 0, 0, 0);
        acc2 = __builtin_amdgcn_mfma_f32_16x16x32_f16(v2, PF.v, acc2, 0, 0, 0);
        acc3 = __builtin_amdgcn_mfma_f32_16x16x32_f16(v3, PF.v, acc3, 0, 0, 0);
    }

    // ---- per-wave partials -> LDS ----
    if (lane < 16) { sm_m[wid][lc] = m; sm_l[wid][lc] = l; }
    {
        float* sa = sm_acc + (size_t)wid * 64 * 17 + lc;
#pragma unroll
        for (int v = 0; v < 4; ++v) {
            sa[(0 * 16 + lg * 4 + v) * 17] = acc0[v];
            sa[(1 * 16 + lg * 4 + v) * 17] = acc1[v];
            sa[(2 * 16 + lg * 4 + v) * 17] = acc2[v];
            sa[(3 * 16 + lg * 4 + v) * 17] = acc3[v];
        }
    }
    __syncthreads();

    // ---- 8-way merge + residual; thread -> (c = tid>>3, q = 2*(tid&7)+dq) ----
    {
        const int c = tid >> 3;
        const int qb2 = (tid & 7) * 2;
        const float g = gamma[0];
#pragma unroll
        for (int dq = 0; dq < 2; ++dq) {
            const int q = qb2 + dq;
            float M = sm_m[0][q];
#pragma unroll
            for (int w = 1; w < 8; ++w) M = fmaxf(M, sm_m[w][q]);
            float L = 0.f, O = 0.f;
#pragma unroll
            for (int w = 0; w < 8; ++w) {
                const float e = __expf(sm_m[w][q] - M);
                L = fmaf(sm_l[w][q], e, L);
                O = fmaf(sm_acc[(w * 64 + c) * 17 + q], e, O);
            }
            const size_t oi = (size_t)b * CC * NN + (size_t)c * NN + q0 + q;
            out[oi] = fmaf(g, O / L, x[oi]);
        }
    }
}

// ---------------------------------------------------------------------------
extern "C" void kernel_launch(void* const* d_in, const int* in_sizes, int n_in,
                              void* d_out, int out_size, void* d_ws, size_t ws_size,
                              hipStream_t stream)
{
    const float* x     = (const float*)d_in[0];
    const float* Wq    = (const float*)d_in[1];
    const float* Wk    = (const float*)d_in[2];
    const float* Wv    = (const float*)d_in[3];
    const float* gamma = (const float*)d_in[4];
    float* out = (float*)d_out;

    // ws layout: qh 128K | kh 128K | vph 1M
    char* ws = (char*)d_ws;
    _Float16* qh  = (_Float16*)ws;
    _Float16* kh  = qh + (size_t)BB * NN * 8;
    _Float16* vph = kh + (size_t)BB * NN * 8;

    hipLaunchKernelGGL(proj_kernel, dim3(320), dim3(256), 0, stream,
                       x, Wq, Wk, Wv, qh, kh, vph);
    hipLaunchKernelGGL(attn_kernel, dim3(BB * 256), dim3(512), 0, stream,
                       qh, kh, vph, x, gamma, out);
}